// Round 2
// baseline (910.462 us; speedup 1.0000x reference)
//
#include <hip/hip_runtime.h>
#include <hip/hip_bf16.h>

// ---------------------------------------------------------------------------
// MoE FFN, routed top-2 of 8 experts, bf16 MFMA GEMMs.
// D=1024, H=2736 (padded to Hp=2816 = 22*128 = 88*32), T=4096, slots=8192.
// ---------------------------------------------------------------------------

#define T_TOK   4096
#define NEXP    8
#define DIM     1024
#define HID     2736
#define HP      2816
#define NSLOT   8192   // T_TOK * 2

typedef __attribute__((ext_vector_type(8))) short short8;
typedef __attribute__((ext_vector_type(4))) float f32x4;

typedef unsigned int __attribute__((address_space(1))) as1_u32;
typedef unsigned int __attribute__((address_space(3))) as3_u32;

__device__ __forceinline__ void gl_lds16(const void* g, void* s) {
  __builtin_amdgcn_global_load_lds((const as1_u32*)g, (as3_u32*)s, 16, 0, 0);
}

__device__ __forceinline__ unsigned short f2bf(float f) {
  unsigned int u = __float_as_uint(f);
  u = (u + 0x7fffu + ((u >> 16) & 1u)) >> 16;   // round-to-nearest-even
  return (unsigned short)u;
}

// ---------------------------------------------------------------------------
// 1) routing: one wave per token.  Double-precision accumulation so the
//    top-2 selection matches the harness reference even on near-ties.
// ---------------------------------------------------------------------------
__global__ __launch_bounds__(256) void route_kernel(
    const float* __restrict__ x, const float* __restrict__ centroid,
    int* __restrict__ sel, float* __restrict__ wgt, int* __restrict__ counts)
{
  int tok = (blockIdx.x * 256 + threadIdx.x) >> 6;
  int l = threadIdx.x & 63;
  const float* xr = x + (size_t)tok * DIM;

  double dot[NEXP] = {}, cc[NEXP] = {};
  double xx = 0.0;
  for (int i = 0; i < DIM / 64; ++i) {
    int d = l + i * 64;
    double xv = (double)xr[d];
    xx += xv * xv;
#pragma unroll
    for (int e = 0; e < NEXP; ++e) {
      double cv = (double)centroid[e * DIM + d];
      dot[e] += xv * cv;
      cc[e]  += cv * cv;
    }
  }
#pragma unroll
  for (int off = 32; off; off >>= 1) {
    xx += __shfl_xor(xx, off);
#pragma unroll
    for (int e = 0; e < NEXP; ++e) {
      dot[e] += __shfl_xor(dot[e], off);
      cc[e]  += __shfl_xor(cc[e], off);
    }
  }
  if (l == 0) {
    double v0 = -1e300, v1 = -1e300; int i0 = 0, i1 = 0;
#pragma unroll
    for (int e = 0; e < NEXP; ++e) {
      double d2 = xx + cc[e] - 2.0 * dot[e];
      double dist = sqrt(fmax(d2, 1e-12));
      if (dist > v0)      { v1 = v0; i1 = i0; v0 = dist; i0 = e; }
      else if (dist > v1) { v1 = dist; i1 = e; }
    }
    float ex = __expf((float)(v1 - v0));     // stable softmax over [v0, v1]
    float w0 = 1.f / (1.f + ex);
    float w1 = ex  / (1.f + ex);
    sel[tok * 2] = i0; sel[tok * 2 + 1] = i1;
    wgt[tok * 2] = w0; wgt[tok * 2 + 1] = w1;
    atomicAdd(&counts[i0], 1);
    atomicAdd(&counts[i1], 1);
  }
}

// ---------------------------------------------------------------------------
// 2) scan: offsets + zero cursors (single tiny block)
// ---------------------------------------------------------------------------
__global__ void scan_kernel(const int* __restrict__ counts,
                            int* __restrict__ offsets, int* __restrict__ cursors)
{
  if (threadIdx.x == 0) {
    int off = 0;
    for (int e = 0; e < NEXP; ++e) { offsets[e] = off; off += counts[e]; cursors[e] = 0; }
  }
}

// ---------------------------------------------------------------------------
// 3) build compacted per-expert row lists
// ---------------------------------------------------------------------------
__global__ __launch_bounds__(256) void build_kernel(
    const int* __restrict__ sel, const int* __restrict__ offsets,
    int* __restrict__ cursors, int* __restrict__ rowmap, int* __restrict__ slot_of)
{
  int t = blockIdx.x * 256 + threadIdx.x;
  if (t >= T_TOK) return;
#pragma unroll
  for (int k = 0; k < 2; ++k) {
    int e = sel[t * 2 + k];
    int pos = atomicAdd(&cursors[e], 1);
    int slot = offsets[e] + pos;
    rowmap[slot] = t;
    slot_of[t * 2 + k] = slot;
  }
}

// ---------------------------------------------------------------------------
// 4) gather x rows -> contiguous bf16 A matrix
// ---------------------------------------------------------------------------
__global__ __launch_bounds__(256) void gather_kernel(
    const float* __restrict__ x, const int* __restrict__ rowmap,
    unsigned short* __restrict__ xg)
{
  int slot = blockIdx.x;
  int t = rowmap[slot];
  int d = threadIdx.x * 4;
  float4 v = *(const float4*)(x + (size_t)t * DIM + d);
  unsigned long long pk =
      (unsigned long long)f2bf(v.x)
    | ((unsigned long long)f2bf(v.y) << 16)
    | ((unsigned long long)f2bf(v.z) << 32)
    | ((unsigned long long)f2bf(v.w) << 48);
  *(unsigned long long*)(xg + (size_t)slot * DIM + d) = pk;
}

// ---------------------------------------------------------------------------
// 5) transpose + f32->bf16 + zero-pad:  dst[i][j] = (i<C && j<R) ? src[j][i] : 0
//    src: [R][C] f32 (per expert), dst: [DN][DK] bf16 (per expert)
// ---------------------------------------------------------------------------
__global__ __launch_bounds__(256) void transpose_pad(
    const float* __restrict__ src, int R, int C,
    unsigned short* __restrict__ dst, int DN, int DK,
    size_t sstr, size_t dstr)
{
  __shared__ float tile[64][65];
  src += sstr * blockIdx.z;
  dst += dstr * blockIdx.z;
  int i0 = blockIdx.y * 64;       // dst-row block (src cols)
  int j0 = blockIdx.x * 64;       // dst-col block (src rows)
  int tx = threadIdx.x, ty = threadIdx.y;

#pragma unroll
  for (int rr = 0; rr < 4; ++rr) {
    int j = j0 + ty * 4 + rr;     // src row
#pragma unroll
    for (int c = 0; c < 4; ++c) {
      int i = i0 + tx * 4 + c;    // src col
      float v = 0.f;
      if (j < R && i < C) v = src[(size_t)j * C + i];
      tile[ty * 4 + rr][tx * 4 + c] = v;
    }
  }
  __syncthreads();
#pragma unroll
  for (int rr = 0; rr < 4; ++rr) {
    int i = i0 + ty * 4 + rr;     // dst row
    unsigned long long pk = 0;
#pragma unroll
    for (int c = 0; c < 4; ++c) {
      float v = tile[tx * 4 + c][ty * 4 + rr];
      pk |= (unsigned long long)f2bf(v) << (16 * c);
    }
    *(unsigned long long*)(dst + (size_t)i * DK + j0 + tx * 4) = pk;
  }
}

// ---------------------------------------------------------------------------
// 6) fused gate/up GEMM + SiLU*up epilogue -> h (bf16, [NSLOT][HP])
//    A = xg [NSLOT][DIM], B^T = WgT/W1T [E][HP][DIM]
//    128x128 tile, BK=32, 4 waves (2x2), mfma 16x16x32 bf16
// ---------------------------------------------------------------------------
__global__ __launch_bounds__(256) void gemm1_fused(
    const unsigned short* __restrict__ xg,
    const unsigned short* __restrict__ WgT,
    const unsigned short* __restrict__ W1T,
    const float* __restrict__ bg, const float* __restrict__ b1,
    const int* __restrict__ counts, const int* __restrict__ offsets,
    unsigned short* __restrict__ h)
{
  int e = blockIdx.y >> 5;
  int rowtile = blockIdx.y & 31;
  int cnt = counts[e];
  if (rowtile * 128 >= cnt) return;
  int ntile = blockIdx.x;                  // 0..21
  int row_base = offsets[e] + rowtile * 128;

  __shared__ unsigned short As[128 * 32];
  __shared__ unsigned short Bg[128 * 32];
  __shared__ unsigned short Bu[128 * 32];

  int tid = threadIdx.x;
  int l = tid & 63;
  int w = tid >> 6;
  int wr = w >> 1, wc = w & 1;

  f32x4 accg[4][4] = {};
  f32x4 accu[4][4] = {};

  int sr = w * 16 + (l >> 2);              // staging row (iter 0)
  int sk = (l & 3) * 8;                    // staging k element offset

  const size_t brow = ((size_t)e * HP + (size_t)ntile * 128) * DIM;

  for (int k0 = 0; k0 < DIM; k0 += 32) {
#pragma unroll
    for (int it = 0; it < 2; ++it) {
      int r = sr + it * 64;
      int slot = row_base + r; slot = slot > (NSLOT - 1) ? (NSLOT - 1) : slot;
      gl_lds16(xg + (size_t)slot * DIM + k0 + sk,
               (char*)As + w * 1024 + it * 4096);
      gl_lds16(WgT + brow + (size_t)r * DIM + k0 + sk,
               (char*)Bg + w * 1024 + it * 4096);
      gl_lds16(W1T + brow + (size_t)r * DIM + k0 + sk,
               (char*)Bu + w * 1024 + it * 4096);
    }
    __syncthreads();

    short8 af[4], gf[4], uf[4];
    int lr = l & 15;
    int lk = (l >> 4) * 16;                // byte offset of k-chunk
#pragma unroll
    for (int m = 0; m < 4; ++m)
      af[m] = *(const short8*)((const char*)As + (wr * 64 + m * 16 + lr) * 64 + lk);
#pragma unroll
    for (int n = 0; n < 4; ++n) {
      gf[n] = *(const short8*)((const char*)Bg + (wc * 64 + n * 16 + lr) * 64 + lk);
      uf[n] = *(const short8*)((const char*)Bu + (wc * 64 + n * 16 + lr) * 64 + lk);
    }
#pragma unroll
    for (int m = 0; m < 4; ++m)
#pragma unroll
      for (int n = 0; n < 4; ++n) {
        accg[m][n] = __builtin_amdgcn_mfma_f32_16x16x32_bf16(af[m], gf[n], accg[m][n], 0, 0, 0);
        accu[m][n] = __builtin_amdgcn_mfma_f32_16x16x32_bf16(af[m], uf[n], accu[m][n], 0, 0, 0);
      }
    __syncthreads();
  }

  // epilogue: h = silu(g + bg) * (u + b1); pad region (n>=HID) -> exact 0
  int lr = l & 15, lq = l >> 4;
#pragma unroll
  for (int n = 0; n < 4; ++n) {
    int ng = ntile * 128 + wc * 64 + n * 16 + lr;        // < HP
    float bgv = 0.f, b1v = 0.f;
    if (ng < HID) { bgv = bg[(size_t)e * HID + ng]; b1v = b1[(size_t)e * HID + ng]; }
#pragma unroll
    for (int m = 0; m < 4; ++m)
#pragma unroll
      for (int jj = 0; jj < 4; ++jj) {
        int tr = wr * 64 + m * 16 + lq * 4 + jj;         // row WITHIN tile
        if (rowtile * 128 + tr < cnt) {
          float g = accg[m][n][jj] + bgv;
          float u = accu[m][n][jj] + b1v;
          float hv = g / (1.f + __expf(-g)) * u;
          h[(size_t)(row_base + tr) * HP + ng] = f2bf(hv);
        }
      }
  }
}

// ---------------------------------------------------------------------------
// 7) down GEMM: y = h @ W2  (A = h [NSLOT][HP], B^T = W2T [E][DIM][HP])
// ---------------------------------------------------------------------------
__global__ __launch_bounds__(256) void gemm2_kernel(
    const unsigned short* __restrict__ h,
    const unsigned short* __restrict__ W2T,
    const int* __restrict__ counts, const int* __restrict__ offsets,
    float* __restrict__ y)
{
  int e = blockIdx.y >> 5;
  int rowtile = blockIdx.y & 31;
  int cnt = counts[e];
  if (rowtile * 128 >= cnt) return;
  int ntile = blockIdx.x;                  // 0..7
  int row_base = offsets[e] + rowtile * 128;

  __shared__ unsigned short As[128 * 32];
  __shared__ unsigned short Bs[128 * 32];

  int tid = threadIdx.x;
  int l = tid & 63;
  int w = tid >> 6;
  int wr = w >> 1, wc = w & 1;

  f32x4 acc[4][4] = {};

  int sr = w * 16 + (l >> 2);
  int sk = (l & 3) * 8;
  const size_t brow = ((size_t)e * DIM + (size_t)ntile * 128) * HP;

  for (int k0 = 0; k0 < HP; k0 += 32) {
#pragma unroll
    for (int it = 0; it < 2; ++it) {
      int r = sr + it * 64;
      int slot = row_base + r; slot = slot > (NSLOT - 1) ? (NSLOT - 1) : slot;
      gl_lds16(h + (size_t)slot * HP + k0 + sk,
               (char*)As + w * 1024 + it * 4096);
      gl_lds16(W2T + brow + (size_t)r * HP + k0 + sk,
               (char*)Bs + w * 1024 + it * 4096);
    }
    __syncthreads();

    short8 af[4], bf[4];
    int lr = l & 15;
    int lk = (l >> 4) * 16;
#pragma unroll
    for (int m = 0; m < 4; ++m)
      af[m] = *(const short8*)((const char*)As + (wr * 64 + m * 16 + lr) * 64 + lk);
#pragma unroll
    for (int n = 0; n < 4; ++n)
      bf[n] = *(const short8*)((const char*)Bs + (wc * 64 + n * 16 + lr) * 64 + lk);
#pragma unroll
    for (int m = 0; m < 4; ++m)
#pragma unroll
      for (int n = 0; n < 4; ++n)
        acc[m][n] = __builtin_amdgcn_mfma_f32_16x16x32_bf16(af[m], bf[n], acc[m][n], 0, 0, 0);
    __syncthreads();
  }

  int lr = l & 15, lq = l >> 4;
#pragma unroll
  for (int n = 0; n < 4; ++n) {
    int ng = ntile * 128 + wc * 64 + n * 16 + lr;        // < DIM
#pragma unroll
    for (int m = 0; m < 4; ++m)
#pragma unroll
      for (int jj = 0; jj < 4; ++jj) {
        int tr = wr * 64 + m * 16 + lq * 4 + jj;         // row WITHIN tile
        if (rowtile * 128 + tr < cnt)
          y[(size_t)(row_base + tr) * DIM + ng] = acc[m][n][jj];
      }
  }
}

// ---------------------------------------------------------------------------
// 8) combine: out[t] = sum_k w_k * (y[slot_k] + b2[e_k])
// ---------------------------------------------------------------------------
__global__ __launch_bounds__(256) void combine_kernel(
    const float* __restrict__ y, const float* __restrict__ b2,
    const int* __restrict__ sel, const float* __restrict__ wgt,
    const int* __restrict__ slot_of, float* __restrict__ out)
{
  int t = blockIdx.x;
  int d = threadIdx.x * 4;
  int e0 = sel[t * 2], e1 = sel[t * 2 + 1];
  float w0 = wgt[t * 2], w1 = wgt[t * 2 + 1];
  int s0 = slot_of[t * 2], s1 = slot_of[t * 2 + 1];
  float4 y0 = *(const float4*)(y + (size_t)s0 * DIM + d);
  float4 y1 = *(const float4*)(y + (size_t)s1 * DIM + d);
  float4 c0 = *(const float4*)(b2 + (size_t)e0 * DIM + d);
  float4 c1 = *(const float4*)(b2 + (size_t)e1 * DIM + d);
  float4 o;
  o.x = w0 * (y0.x + c0.x) + w1 * (y1.x + c1.x);
  o.y = w0 * (y0.y + c0.y) + w1 * (y1.y + c1.y);
  o.z = w0 * (y0.z + c0.z) + w1 * (y1.z + c1.z);
  o.w = w0 * (y0.w + c0.w) + w1 * (y1.w + c1.w);
  *(float4*)(out + (size_t)t * DIM + d) = o;
}

// ---------------------------------------------------------------------------
extern "C" void kernel_launch(void* const* d_in, const int* in_sizes, int n_in,
                              void* d_out, int out_size, void* d_ws, size_t ws_size,
                              hipStream_t stream)
{
  const float* x        = (const float*)d_in[0];
  const float* centroid = (const float*)d_in[1];
  const float* Wg       = (const float*)d_in[2];
  const float* bg       = (const float*)d_in[3];
  const float* W1       = (const float*)d_in[4];
  const float* b1       = (const float*)d_in[5];
  const float* W2       = (const float*)d_in[6];
  const float* b2       = (const float*)d_in[7];
  float* out = (float*)d_out;

  char* ws = (char*)d_ws;
  // fixed layout
  int*   counts  = (int*)ws;            // 8
  int*   offsets = counts + 8;          // 8
  int*   cursors = counts + 16;         // 8
  size_t off = 256;
  auto alloc = [&](size_t bytes) { size_t a = off; off += (bytes + 255) & ~(size_t)255; return a; };
  int*   sel     = (int*)  (ws + alloc((size_t)T_TOK * 2 * 4));
  float* wgt     = (float*)(ws + alloc((size_t)T_TOK * 2 * 4));
  int*   slot_of = (int*)  (ws + alloc((size_t)T_TOK * 2 * 4));
  int*   rowmap  = (int*)  (ws + alloc((size_t)NSLOT * 4));
  unsigned short* xg  = (unsigned short*)(ws + alloc((size_t)NSLOT * DIM * 2));
  unsigned short* WgT = (unsigned short*)(ws + alloc((size_t)NEXP * HP * DIM * 2));
  unsigned short* W1T = (unsigned short*)(ws + alloc((size_t)NEXP * HP * DIM * 2));
  unsigned short* W2T = (unsigned short*)(ws + alloc((size_t)NEXP * DIM * HP * 2));
  unsigned short* hbuf= (unsigned short*)(ws + alloc((size_t)NSLOT * HP * 2));
  float* ybuf         = (float*)         (ws + alloc((size_t)NSLOT * DIM * 4));
  (void)ws_size; (void)n_in; (void)in_sizes; (void)out_size;

  hipMemsetAsync(counts, 0, 96, stream);

  route_kernel<<<T_TOK / 4, 256, 0, stream>>>(x, centroid, sel, wgt, counts);
  scan_kernel<<<1, 64, 0, stream>>>(counts, offsets, cursors);
  build_kernel<<<T_TOK / 256, 256, 0, stream>>>(sel, offsets, cursors, rowmap, slot_of);
  gather_kernel<<<NSLOT, 256, 0, stream>>>(x, rowmap, xg);

  // weight transposes (f32 -> bf16, padded)
  transpose_pad<<<dim3(DIM / 64, HP / 64, NEXP), dim3(16, 16), 0, stream>>>(
      Wg, DIM, HID, WgT, HP, DIM, (size_t)DIM * HID, (size_t)HP * DIM);
  transpose_pad<<<dim3(DIM / 64, HP / 64, NEXP), dim3(16, 16), 0, stream>>>(
      W1, DIM, HID, W1T, HP, DIM, (size_t)DIM * HID, (size_t)HP * DIM);
  transpose_pad<<<dim3(HP / 64, DIM / 64, NEXP), dim3(16, 16), 0, stream>>>(
      W2, HID, DIM, W2T, DIM, HP, (size_t)HID * DIM, (size_t)DIM * HP);

  gemm1_fused<<<dim3(HP / 128, NEXP * 32), 256, 0, stream>>>(
      xg, WgT, W1T, bg, b1, counts, offsets, hbuf);
  gemm2_kernel<<<dim3(DIM / 128, NEXP * 32), 256, 0, stream>>>(
      hbuf, W2T, counts, offsets, ybuf);

  combine_kernel<<<T_TOK, 256, 0, stream>>>(ybuf, b2, sel, wgt, slot_of, out);
}